// Round 1
// baseline (491.017 us; speedup 1.0000x reference)
//
#include <hip/hip_runtime.h>

#define N_NODES 200000
#define DIM 256
#define G_SEG 1024
#define MT 64         // rows per block; N_NODES % MT == 0 (3125 blocks, no tail)
#define LDA 264       // LDS row stride in bf16 elems (256 + 8 pad)
#define NT 4          // 16-row m-tiles per block
#define KSTEPS 8      // 256 / 32

typedef __bf16 bf16x8 __attribute__((ext_vector_type(8)));
typedef __bf16 bf16x4v __attribute__((ext_vector_type(4)));
typedef float f32x4 __attribute__((ext_vector_type(4)));
typedef unsigned short us16_t __attribute__((ext_vector_type(16)));
typedef unsigned short us8_t __attribute__((ext_vector_type(8)));
typedef unsigned short us4_t __attribute__((ext_vector_type(4)));

__device__ __forceinline__ unsigned short f2bf(float f) {
  unsigned int u = __float_as_uint(f);
  u = u + 0x7FFFu + ((u >> 16) & 1u);   // round-to-nearest-even (k_prep only)
  return (unsigned short)(u >> 16);
}

__device__ __forceinline__ bf16x8 ld_frag(const unsigned short* p) {
  us8_t r = *(const us8_t*)p;
  return __builtin_bit_cast(bf16x8, r);
}

__device__ __forceinline__ float silu(float v) {
  // v * rcp(1+exp(-v)); rcp approx (~1ulp) is far below bf16 noise
  return v * __builtin_amdgcn_rcpf(1.f + __expf(-v));
}

// f32x4 -> 4 bf16 via HW v_cvt_pk_bf16_f32 (RNE), single 8B LDS store.
__device__ __forceinline__ void st_bf4(unsigned short* dst, f32x4 x) {
  *(bf16x4v*)dst = __builtin_convertvector(x, bf16x4v);
}

// Stage MT rows x 256 cols of fp32 X into LDS as bf16 (padded stride LDA).
// N_NODES % MT == 0 -> no bounds check.
__device__ __forceinline__ void stage_x(const float* __restrict__ X,
                                        unsigned short* A, int base, int tid) {
  #pragma unroll 4
  for (int i = 0; i < 16; ++i) {
    int flat = i * 256 + tid;          // 0..4095
    int row = flat >> 6;               // 0..63
    int c4 = flat & 63;                // float4 index within row
    float4 v = *(const float4*)(X + (size_t)(base + row) * DIM + c4 * 4);
    f32x4 f = {v.x, v.y, v.z, v.w};
    st_bf4(A + row * LDA + c4 * 4, f);
  }
}

// Transposed GEMM: D[feature][node] = W_tile x X_tile.
// wlane = Wb + (wcol0+l15)*256 + quad*8 ; alane = a_lds + l15*LDA + quad*8.
// All inner loads are base + compile-time offset (immediate-folded).
// acc[t][u]: node = t*16 + (lane&15), feature = wcol0 + u*16 + (lane>>4)*4 + r.
__device__ __forceinline__ void gemm_k256_T(const unsigned short* __restrict__ wlane,
                                            const unsigned short* __restrict__ alane,
                                            f32x4 acc[NT][4]) {
  #pragma unroll
  for (int ks = 0; ks < KSTEPS; ++ks) {
    bf16x8 wfr[4];
    #pragma unroll
    for (int u = 0; u < 4; ++u)
      wfr[u] = ld_frag(wlane + u * 16 * 256 + ks * 32);
    #pragma unroll
    for (int t = 0; t < NT; ++t) {
      bf16x8 xfr = ld_frag(alane + t * 16 * LDA + ks * 32);
      #pragma unroll
      for (int u = 0; u < 4; ++u)
        acc[t][u] = __builtin_amdgcn_mfma_f32_16x16x32_bf16(wfr[u], xfr, acc[t][u], 0, 0, 0);
    }
  }
}

__device__ __forceinline__ void zero_acc(f32x4 acc[NT][4]) {
  #pragma unroll
  for (int t = 0; t < NT; ++t)
    #pragma unroll
    for (int u = 0; u < 4; ++u)
      acc[t][u] = (f32x4){0.f, 0.f, 0.f, 0.f};
}

// Kernel 0: zero out + denom (blocks 0..1024), transpose weights to bf16 [n][k]
// with coalesced LDS tiles (blocks 1025..1040).
__global__ __launch_bounds__(256) void k_prep(
    const float* __restrict__ W1, const float* __restrict__ W2,
    const float* __restrict__ W3, const float* __restrict__ aW1,
    unsigned short* __restrict__ Wb1, unsigned short* __restrict__ Wb2,
    unsigned short* __restrict__ Wb3, unsigned short* __restrict__ aWb1,
    float* __restrict__ out, float* __restrict__ denom) {
  __shared__ float tlds[64][257];
  int b = blockIdx.x, tid = threadIdx.x;
  if (b < 1024) {
    out[b * 256 + tid] = 0.f;
    return;
  }
  if (b == 1024) {
    #pragma unroll
    for (int i = 0; i < 4; ++i) denom[tid * 4 + i] = 0.f;
    return;
  }
  int bb = b - 1025;                  // 0..15
  int mat = bb >> 2, kc = bb & 3, k0 = kc * 64;
  const float* W = (mat == 0) ? W1 : (mat == 1) ? W2 : (mat == 2) ? W3 : aW1;
  unsigned short* Wb = (mat == 0) ? Wb1 : (mat == 1) ? Wb2 : (mat == 2) ? Wb3 : aWb1;
  #pragma unroll 8
  for (int i = 0; i < 64; ++i)
    tlds[i][tid] = W[(size_t)(k0 + i) * 256 + tid];
  __syncthreads();
  #pragma unroll
  for (int rep = 0; rep < 4; ++rep) {
    int flat = rep * 256 + tid;       // 0..1023
    int n = flat >> 2, c = flat & 3;
    us16_t v;
    #pragma unroll
    for (int j = 0; j < 16; ++j) v[j] = f2bf(tlds[c * 16 + j][n]);
    *(us16_t*)(Wb + (size_t)n * 256 + k0 + c * 16) = v;
  }
}

// Fused heavy kernel: one staging of X, attention GEMM + 3-stage MLP,
// unnormalized weighted segment sums into out + denom.
// MT=64 -> a_lds 33.8 KB -> 4 blocks/CU (16 waves/CU) vs 2 at MT=128.
__global__ __launch_bounds__(256, 4) void k_fused(
    const float* __restrict__ X, const int* __restrict__ batch,
    const unsigned short* __restrict__ aWb1, const float* __restrict__ ab1,
    const float* __restrict__ aW2, const float* __restrict__ ab2,
    const unsigned short* __restrict__ Wb1, const float* __restrict__ b1,
    const unsigned short* __restrict__ Wb2, const float* __restrict__ b2,
    const unsigned short* __restrict__ Wb3, const float* __restrict__ b3,
    float* __restrict__ out, float* __restrict__ denom) {
  __shared__ unsigned short a_lds[MT * LDA];   // 33792 B
  __shared__ float l_lds[MT];
  __shared__ float ew0[MT], ew1[MT];
  __shared__ float seg_lds[2];
  int tid = threadIdx.x;
  int base = blockIdx.x * MT;
  stage_x(X, a_lds, base, tid);
  if (tid < MT) l_lds[tid] = 0.f;
  if (tid < 2) seg_lds[tid] = 0.f;
  __syncthreads();

  int wave = tid >> 6, lane = tid & 63, quad = lane >> 4, l15 = lane & 15;
  int wcol0 = wave * 64;
  int fq = wcol0 + quad * 4;          // this lane's feature base for u=0
  const unsigned short* alane = a_lds + l15 * LDA + quad * 8;
  unsigned short* elane = a_lds + l15 * LDA + fq;     // epilogue store base
  int woff = (wcol0 + l15) * 256 + quad * 8;
  f32x4 acc[NT][4];

  // ---- attention logits GEMM ----
  zero_acc(acc);
  gemm_k256_T(aWb1 + woff, alane, acc);
  {
    float4 ab1c[4], aw2c[4];
    #pragma unroll
    for (int u = 0; u < 4; ++u) {
      ab1c[u] = *(const float4*)(ab1 + fq + u * 16);
      aw2c[u] = *(const float4*)(aW2 + fq + u * 16);
    }
    #pragma unroll
    for (int t = 0; t < NT; ++t) {
      float p = 0.f;
      #pragma unroll
      for (int u = 0; u < 4; ++u) {
        const float* bb = (const float*)&ab1c[u];
        const float* ww = (const float*)&aw2c[u];
        #pragma unroll
        for (int r = 0; r < 4; ++r)
          p += silu(acc[t][u][r] + bb[r]) * ww[r];
      }
      p += __shfl_xor(p, 16); p += __shfl_xor(p, 32);
      if (quad == 0) atomicAdd(&l_lds[t * 16 + l15], p);
    }
  }

  // ---- MLP stage 1: h1 = silu(X @ W1 + b1) ----
  zero_acc(acc);
  gemm_k256_T(Wb1 + woff, alane, acc);
  __syncthreads();   // all waves done with a_lds reads AND l_lds atomics
  if (tid < MT) {
    float e = __expf(l_lds[tid] + ab2[0]);
    int ds = batch[base + tid] - batch[base];   // 0 or 1 (min seg size 195 > 64)
    ew0[tid] = ds ? 0.f : e;
    ew1[tid] = ds ? e : 0.f;
    atomicAdd(&seg_lds[ds], e);
  }
  {
    float4 bc[4];
    #pragma unroll
    for (int u = 0; u < 4; ++u) bc[u] = *(const float4*)(b1 + fq + u * 16);
    #pragma unroll
    for (int t = 0; t < NT; ++t)
      #pragma unroll
      for (int u = 0; u < 4; ++u) {
        const float* bb = (const float*)&bc[u];
        f32x4 h;
        #pragma unroll
        for (int r = 0; r < 4; ++r)
          h[r] = silu(acc[t][u][r] + bb[r]);
        st_bf4(elane + t * 16 * LDA + u * 16, h);
      }
  }
  __syncthreads();

  // ---- MLP stage 2: h2 = silu(h1 @ W2 + b2) ----
  zero_acc(acc);
  gemm_k256_T(Wb2 + woff, alane, acc);
  __syncthreads();
  {
    float4 bc[4];
    #pragma unroll
    for (int u = 0; u < 4; ++u) bc[u] = *(const float4*)(b2 + fq + u * 16);
    #pragma unroll
    for (int t = 0; t < NT; ++t)
      #pragma unroll
      for (int u = 0; u < 4; ++u) {
        const float* bb = (const float*)&bc[u];
        f32x4 h;
        #pragma unroll
        for (int r = 0; r < 4; ++r)
          h[r] = silu(acc[t][u][r] + bb[r]);
        st_bf4(elane + t * 16 * LDA + u * 16, h);
      }
  }
  __syncthreads();

  // ---- MLP stage 3: x = h2 @ W3 + b3, weighted segment reduce ----
  zero_acc(acc);
  gemm_k256_T(Wb3 + woff, alane, acc);
  {
    float4 bc[4];
    #pragma unroll
    for (int u = 0; u < 4; ++u) bc[u] = *(const float4*)(b3 + fq + u * 16);
    float s0a[4][4], s1a[4][4];
    #pragma unroll
    for (int u = 0; u < 4; ++u)
      #pragma unroll
      for (int r = 0; r < 4; ++r) { s0a[u][r] = 0.f; s1a[u][r] = 0.f; }
    #pragma unroll
    for (int t = 0; t < NT; ++t) {
      float w0 = ew0[t * 16 + l15];
      float w1 = ew1[t * 16 + l15];
      #pragma unroll
      for (int u = 0; u < 4; ++u) {
        const float* bb = (const float*)&bc[u];
        #pragma unroll
        for (int r = 0; r < 4; ++r) {
          float x = acc[t][u][r] + bb[r];
          s0a[u][r] += x * w0;
          s1a[u][r] += x * w1;
        }
      }
    }
    int s0 = batch[base];
    #pragma unroll
    for (int u = 0; u < 4; ++u)
      #pragma unroll
      for (int r = 0; r < 4; ++r) {
        float a0 = s0a[u][r];
        a0 += __shfl_xor(a0, 1); a0 += __shfl_xor(a0, 2);
        a0 += __shfl_xor(a0, 4); a0 += __shfl_xor(a0, 8);
        float a1 = s1a[u][r];
        a1 += __shfl_xor(a1, 1); a1 += __shfl_xor(a1, 2);
        a1 += __shfl_xor(a1, 4); a1 += __shfl_xor(a1, 8);
        if (l15 == 0) {
          int col = fq + u * 16 + r;
          atomicAdd(&out[(size_t)s0 * 256 + col], a0);
          if (s0 + 1 < G_SEG && a1 != 0.f)
            atomicAdd(&out[(size_t)(s0 + 1) * 256 + col], a1);
        }
      }
    if (tid < 2) {
      float v = seg_lds[tid];
      if (v != 0.f) atomicAdd(&denom[s0 + tid], v);
    }
  }
}

// Kernel 2: out[g][c] /= denom[g]
__global__ __launch_bounds__(256) void k_final(float* __restrict__ out,
                                               const float* __restrict__ denom) {
  int b = blockIdx.x, tid = threadIdx.x;
  out[b * 256 + tid] *= __builtin_amdgcn_rcpf(denom[b]);
}

extern "C" void kernel_launch(void* const* d_in, const int* in_sizes, int n_in,
                              void* d_out, int out_size, void* d_ws, size_t ws_size,
                              hipStream_t stream) {
  const float* X    = (const float*)d_in[0];
  const int* batch  = (const int*)d_in[1];
  const float* W1  = (const float*)d_in[3];
  const float* b1  = (const float*)d_in[4];
  const float* W2  = (const float*)d_in[5];
  const float* b2  = (const float*)d_in[6];
  const float* W3  = (const float*)d_in[7];
  const float* b3  = (const float*)d_in[8];
  const float* aW1 = (const float*)d_in[9];
  const float* ab1 = (const float*)d_in[10];
  const float* aW2 = (const float*)d_in[11];
  const float* ab2 = (const float*)d_in[12];
  float* out = (float*)d_out;

  char* ws = (char*)d_ws;
  unsigned short* Wb1  = (unsigned short*)(ws);
  unsigned short* Wb2  = (unsigned short*)(ws + 131072);
  unsigned short* Wb3  = (unsigned short*)(ws + 262144);
  unsigned short* aWb1 = (unsigned short*)(ws + 393216);
  float* denom = (float*)(ws + 524288);

  hipLaunchKernelGGL(k_prep, dim3(1041), dim3(256), 0, stream,
                     W1, W2, W3, aW1, Wb1, Wb2, Wb3, aWb1, out, denom);
  int nblk = N_NODES / MT;  // 3125
  hipLaunchKernelGGL(k_fused, dim3(nblk), dim3(256), 0, stream,
                     X, batch, aWb1, ab1, aW2, ab2,
                     Wb1, b1, Wb2, b2, Wb3, b3, out, denom);
  hipLaunchKernelGGL(k_final, dim3(G_SEG), dim3(256), 0, stream, out, denom);
}

// Round 2
// 440.680 us; speedup vs baseline: 1.1142x; 1.1142x over previous
//
#include <hip/hip_runtime.h>

#define N_NODES 200000
#define DIM 256
#define G_SEG 1024
#define MT 128        // rows per block
#define LDA 264       // LDS row stride in bf16 elems (256 + 8 pad)
#define NT 8          // 16-row m-tiles per block
#define KSTEPS 8      // 256 / 32

typedef __bf16 bf16x8 __attribute__((ext_vector_type(8)));
typedef __bf16 bf16x4v __attribute__((ext_vector_type(4)));
typedef float f32x4 __attribute__((ext_vector_type(4)));
typedef unsigned short us16_t __attribute__((ext_vector_type(16)));
typedef unsigned short us8_t __attribute__((ext_vector_type(8)));
typedef unsigned short us4_t __attribute__((ext_vector_type(4)));

__device__ __forceinline__ unsigned short f2bf(float f) {
  unsigned int u = __float_as_uint(f);
  u = u + 0x7FFFu + ((u >> 16) & 1u);   // round-to-nearest-even (k_prep only)
  return (unsigned short)(u >> 16);
}

__device__ __forceinline__ bf16x8 ld_frag(const unsigned short* p) {
  us8_t r = *(const us8_t*)p;
  return __builtin_bit_cast(bf16x8, r);
}

__device__ __forceinline__ float silu(float v) {
  // v * rcp(1+exp(-v)); rcp approx (~1ulp) is far below bf16 noise
  return v * __builtin_amdgcn_rcpf(1.f + __expf(-v));
}

// f32x4 -> 4 bf16 via HW v_cvt_pk_bf16_f32 (RNE), single 8B LDS store.
__device__ __forceinline__ void st_bf4(unsigned short* dst, f32x4 x) {
  *(bf16x4v*)dst = __builtin_convertvector(x, bf16x4v);
}

// Stage 128 rows x 256 cols of fp32 X into LDS as bf16 (padded stride LDA).
__device__ __forceinline__ void stage_x(const float* __restrict__ X,
                                        unsigned short* A, int base, int tid) {
  #pragma unroll 4
  for (int i = 0; i < 32; ++i) {
    int flat = i * 256 + tid;          // 0..8191
    int row = flat >> 6;               // 0..127
    int c4 = flat & 63;                // float4 index within row
    int grow = base + row;
    float4 v = make_float4(0.f, 0.f, 0.f, 0.f);
    if (grow < N_NODES) v = *(const float4*)(X + (size_t)grow * DIM + c4 * 4);
    f32x4 f = {v.x, v.y, v.z, v.w};
    st_bf4(A + row * LDA + c4 * 4, f);
  }
}

// Transposed GEMM: D[feature][node] = W_tile x X_tile.
// Weights are in fragment-linear layout: element (wave,ks,u,lane,j) at
// ushort offset ((wave*8+ks)*4+u)*512 + lane*8 + j holding
// W[row = wave*64 + u*16 + (lane&15)][k = ks*32 + (lane>>4)*8 + j].
// -> every fragment load is 64 lanes x 16B fully coalesced (1 KB).
// wlane = Wb + wave*16384 + lane*8 ; alane = a_lds + l15*LDA + quad*8.
// acc[t][u]: node = t*16 + (lane&15), feature = wcol0 + u*16 + (lane>>4)*4 + r.
__device__ __forceinline__ void gemm_k256_T(const unsigned short* __restrict__ wlane,
                                            const unsigned short* alane,
                                            f32x4 acc[NT][4]) {
  bf16x8 wcur[4], wnxt[4];
  #pragma unroll
  for (int u = 0; u < 4; ++u) wcur[u] = ld_frag(wlane + u * 512);
  #pragma unroll
  for (int ks = 0; ks < KSTEPS; ++ks) {
    if (ks + 1 < KSTEPS) {
      #pragma unroll
      for (int u = 0; u < 4; ++u)
        wnxt[u] = ld_frag(wlane + ((ks + 1) * 4 + u) * 512);
    }
    #pragma unroll
    for (int t = 0; t < NT; ++t) {
      bf16x8 xfr = ld_frag(alane + t * 16 * LDA + ks * 32);
      #pragma unroll
      for (int u = 0; u < 4; ++u)
        acc[t][u] = __builtin_amdgcn_mfma_f32_16x16x32_bf16(wcur[u], xfr, acc[t][u], 0, 0, 0);
    }
    #pragma unroll
    for (int u = 0; u < 4; ++u) wcur[u] = wnxt[u];
  }
}

__device__ __forceinline__ void zero_acc(f32x4 acc[NT][4]) {
  #pragma unroll
  for (int t = 0; t < NT; ++t)
    #pragma unroll
    for (int u = 0; u < 4; ++u)
      acc[t][u] = (f32x4){0.f, 0.f, 0.f, 0.f};
}

// Kernel 0: zero out + denom (blocks 0..1024); transpose weights to bf16
// fragment-linear layout (blocks 1025..1040, one per matrix x k-chunk).
__global__ __launch_bounds__(256) void k_prep(
    const float* __restrict__ W1, const float* __restrict__ W2,
    const float* __restrict__ W3, const float* __restrict__ aW1,
    unsigned short* __restrict__ Wb1, unsigned short* __restrict__ Wb2,
    unsigned short* __restrict__ Wb3, unsigned short* __restrict__ aWb1,
    float* __restrict__ out, float* __restrict__ denom) {
  __shared__ float tlds[64][257];
  int b = blockIdx.x, tid = threadIdx.x;
  if (b < 1024) {
    out[b * 256 + tid] = 0.f;
    return;
  }
  if (b == 1024) {
    #pragma unroll
    for (int i = 0; i < 4; ++i) denom[tid * 4 + i] = 0.f;
    return;
  }
  int bb = b - 1025;                  // 0..15
  int mat = bb >> 2, kc = bb & 3, k0 = kc * 64;
  const float* W = (mat == 0) ? W1 : (mat == 1) ? W2 : (mat == 2) ? W3 : aW1;
  unsigned short* Wb = (mat == 0) ? Wb1 : (mat == 1) ? Wb2 : (mat == 2) ? Wb3 : aWb1;
  #pragma unroll 8
  for (int i = 0; i < 64; ++i)
    tlds[i][tid] = W[(size_t)(k0 + i) * 256 + tid];
  __syncthreads();
  // emit fragment-linear: 2048 us8 chunks for this k-chunk
  #pragma unroll
  for (int i = 0; i < 8; ++i) {
    int idx = i * 256 + tid;          // 0..2047
    int lane = idx & 63;
    int u = (idx >> 6) & 3;
    int ksl = (idx >> 8) & 1;         // 2 ks values per 64-k chunk
    int wv = idx >> 9;                // 0..3
    int quad = lane >> 4, l15 = lane & 15;
    int row = wv * 64 + u * 16 + l15;
    int ks = kc * 2 + ksl;
    us8_t v;
    #pragma unroll
    for (int j = 0; j < 8; ++j)
      v[j] = f2bf(tlds[ksl * 32 + quad * 8 + j][row]);
    *(us8_t*)(Wb + (size_t)(((wv * 8 + ks) * 4 + u) * 512 + lane * 8)) = v;
  }
}

// Fused heavy kernel: one staging of X, attention GEMM + 3-stage MLP,
// unnormalized weighted segment sums into out + denom.
__global__ __launch_bounds__(256, 2) void k_fused(
    const float* __restrict__ X, const int* __restrict__ batch,
    const unsigned short* __restrict__ aWb1, const float* __restrict__ ab1,
    const float* __restrict__ aW2, const float* __restrict__ ab2,
    const unsigned short* __restrict__ Wb1, const float* __restrict__ b1,
    const unsigned short* __restrict__ Wb2, const float* __restrict__ b2,
    const unsigned short* __restrict__ Wb3, const float* __restrict__ b3,
    float* __restrict__ out, float* __restrict__ denom) {
  __shared__ unsigned short a_lds[MT * LDA];
  __shared__ float l_lds[MT];
  __shared__ float ew0[MT], ew1[MT];
  __shared__ float seg_lds[2];
  int tid = threadIdx.x;
  int base = blockIdx.x * MT;
  stage_x(X, a_lds, base, tid);
  if (tid < MT) l_lds[tid] = 0.f;
  if (tid < 2) seg_lds[tid] = 0.f;
  __syncthreads();

  int wave = tid >> 6, lane = tid & 63, quad = lane >> 4, l15 = lane & 15;
  int wcol0 = wave * 64;
  int fq = wcol0 + quad * 4;          // this lane's feature base for u=0
  const unsigned short* alane = a_lds + l15 * LDA + quad * 8;
  unsigned short* elane = a_lds + l15 * LDA + fq;     // epilogue store base
  int wfoff = wave * 16384 + lane * 8;                // fragment-linear lane base
  f32x4 acc[NT][4];

  // ---- attention logits GEMM ----
  zero_acc(acc);
  gemm_k256_T(aWb1 + wfoff, alane, acc);
  {
    float4 ab1c[4], aw2c[4];
    #pragma unroll
    for (int u = 0; u < 4; ++u) {
      ab1c[u] = *(const float4*)(ab1 + fq + u * 16);
      aw2c[u] = *(const float4*)(aW2 + fq + u * 16);
    }
    #pragma unroll
    for (int t = 0; t < NT; ++t) {
      float p = 0.f;
      #pragma unroll
      for (int u = 0; u < 4; ++u) {
        const float* bb = (const float*)&ab1c[u];
        const float* ww = (const float*)&aw2c[u];
        #pragma unroll
        for (int r = 0; r < 4; ++r)
          p += silu(acc[t][u][r] + bb[r]) * ww[r];
      }
      p += __shfl_xor(p, 16); p += __shfl_xor(p, 32);
      if (quad == 0) atomicAdd(&l_lds[t * 16 + l15], p);
    }
  }

  // ---- MLP stage 1: h1 = silu(X @ W1 + b1) ----
  zero_acc(acc);
  gemm_k256_T(Wb1 + wfoff, alane, acc);
  __syncthreads();   // all waves done with a_lds reads AND l_lds atomics
  if (tid < MT) {
    int grow = base + tid;
    float e = 0.f; int ds = 0;
    if (grow < N_NODES) {
      e = __expf(l_lds[tid] + ab2[0]);
      ds = batch[grow] - batch[base];   // 0 or 1 (min seg size 195 > 128)
    }
    ew0[tid] = ds ? 0.f : e;
    ew1[tid] = ds ? e : 0.f;
    if (e != 0.f) atomicAdd(&seg_lds[ds], e);
  }
  {
    float4 bc[4];
    #pragma unroll
    for (int u = 0; u < 4; ++u) bc[u] = *(const float4*)(b1 + fq + u * 16);
    #pragma unroll
    for (int t = 0; t < NT; ++t)
      #pragma unroll
      for (int u = 0; u < 4; ++u) {
        const float* bb = (const float*)&bc[u];
        f32x4 h;
        #pragma unroll
        for (int r = 0; r < 4; ++r)
          h[r] = silu(acc[t][u][r] + bb[r]);
        st_bf4(elane + t * 16 * LDA + u * 16, h);
      }
  }
  __syncthreads();

  // ---- MLP stage 2: h2 = silu(h1 @ W2 + b2) ----
  zero_acc(acc);
  gemm_k256_T(Wb2 + wfoff, alane, acc);
  __syncthreads();
  {
    float4 bc[4];
    #pragma unroll
    for (int u = 0; u < 4; ++u) bc[u] = *(const float4*)(b2 + fq + u * 16);
    #pragma unroll
    for (int t = 0; t < NT; ++t)
      #pragma unroll
      for (int u = 0; u < 4; ++u) {
        const float* bb = (const float*)&bc[u];
        f32x4 h;
        #pragma unroll
        for (int r = 0; r < 4; ++r)
          h[r] = silu(acc[t][u][r] + bb[r]);
        st_bf4(elane + t * 16 * LDA + u * 16, h);
      }
  }
  __syncthreads();

  // ---- MLP stage 3: x = h2 @ W3 + b3, weighted segment reduce ----
  zero_acc(acc);
  gemm_k256_T(Wb3 + wfoff, alane, acc);
  {
    float4 bc[4];
    #pragma unroll
    for (int u = 0; u < 4; ++u) bc[u] = *(const float4*)(b3 + fq + u * 16);
    float s0a[4][4], s1a[4][4];
    #pragma unroll
    for (int u = 0; u < 4; ++u)
      #pragma unroll
      for (int r = 0; r < 4; ++r) { s0a[u][r] = 0.f; s1a[u][r] = 0.f; }
    #pragma unroll
    for (int t = 0; t < NT; ++t) {
      float w0 = ew0[t * 16 + l15];
      float w1 = ew1[t * 16 + l15];
      #pragma unroll
      for (int u = 0; u < 4; ++u) {
        const float* bb = (const float*)&bc[u];
        #pragma unroll
        for (int r = 0; r < 4; ++r) {
          float x = acc[t][u][r] + bb[r];
          s0a[u][r] += x * w0;
          s1a[u][r] += x * w1;
        }
      }
    }
    int s0 = batch[base];
    #pragma unroll
    for (int u = 0; u < 4; ++u)
      #pragma unroll
      for (int r = 0; r < 4; ++r) {
        float a0 = s0a[u][r];
        a0 += __shfl_xor(a0, 1); a0 += __shfl_xor(a0, 2);
        a0 += __shfl_xor(a0, 4); a0 += __shfl_xor(a0, 8);
        float a1 = s1a[u][r];
        a1 += __shfl_xor(a1, 1); a1 += __shfl_xor(a1, 2);
        a1 += __shfl_xor(a1, 4); a1 += __shfl_xor(a1, 8);
        if (l15 == 0) {
          int col = fq + u * 16 + r;
          atomicAdd(&out[(size_t)s0 * 256 + col], a0);
          if (s0 + 1 < G_SEG && a1 != 0.f)
            atomicAdd(&out[(size_t)(s0 + 1) * 256 + col], a1);
        }
      }
    if (tid < 2) {
      float v = seg_lds[tid];
      if (v != 0.f) atomicAdd(&denom[s0 + tid], v);
    }
  }
}

// Kernel 2: out[g][c] /= denom[g]
__global__ __launch_bounds__(256) void k_final(float* __restrict__ out,
                                               const float* __restrict__ denom) {
  int b = blockIdx.x, tid = threadIdx.x;
  out[b * 256 + tid] *= __builtin_amdgcn_rcpf(denom[b]);
}

extern "C" void kernel_launch(void* const* d_in, const int* in_sizes, int n_in,
                              void* d_out, int out_size, void* d_ws, size_t ws_size,
                              hipStream_t stream) {
  const float* X    = (const float*)d_in[0];
  const int* batch  = (const int*)d_in[1];
  const float* W1  = (const float*)d_in[3];
  const float* b1  = (const float*)d_in[4];
  const float* W2  = (const float*)d_in[5];
  const float* b2  = (const float*)d_in[6];
  const float* W3  = (const float*)d_in[7];
  const float* b3  = (const float*)d_in[8];
  const float* aW1 = (const float*)d_in[9];
  const float* ab1 = (const float*)d_in[10];
  const float* aW2 = (const float*)d_in[11];
  const float* ab2 = (const float*)d_in[12];
  float* out = (float*)d_out;

  char* ws = (char*)d_ws;
  unsigned short* Wb1  = (unsigned short*)(ws);
  unsigned short* Wb2  = (unsigned short*)(ws + 131072);
  unsigned short* Wb3  = (unsigned short*)(ws + 262144);
  unsigned short* aWb1 = (unsigned short*)(ws + 393216);
  float* denom = (float*)(ws + 524288);

  hipLaunchKernelGGL(k_prep, dim3(1041), dim3(256), 0, stream,
                     W1, W2, W3, aW1, Wb1, Wb2, Wb3, aWb1, out, denom);
  int nblk = (N_NODES + MT - 1) / MT;  // 1563
  hipLaunchKernelGGL(k_fused, dim3(nblk), dim3(256), 0, stream,
                     X, batch, aWb1, ab1, aW2, ab2,
                     Wb1, b1, Wb2, b2, Wb3, b3, out, denom);
  hipLaunchKernelGGL(k_final, dim3(G_SEG), dim3(256), 0, stream, out, denom);
}

// Round 3
// 398.910 us; speedup vs baseline: 1.2309x; 1.1047x over previous
//
#include <hip/hip_runtime.h>

#define N_NODES 200000
#define DIM 256
#define G_SEG 1024
#define MT 128        // rows per block
#define LDA 264       // LDS row stride in bf16 elems (256 + 8 pad)
#define NT 8          // 16-row m-tiles per block
#define NU 2          // feature sub-tiles per wave (8 waves x 32 features)
#define KSTEPS 8      // 256 / 32
#define THREADS 512

typedef __bf16 bf16x8 __attribute__((ext_vector_type(8)));
typedef __bf16 bf16x4v __attribute__((ext_vector_type(4)));
typedef float f32x4 __attribute__((ext_vector_type(4)));
typedef unsigned short us16_t __attribute__((ext_vector_type(16)));
typedef unsigned short us8_t __attribute__((ext_vector_type(8)));
typedef unsigned short us4_t __attribute__((ext_vector_type(4)));

__device__ __forceinline__ unsigned short f2bf(float f) {
  unsigned int u = __float_as_uint(f);
  u = u + 0x7FFFu + ((u >> 16) & 1u);   // round-to-nearest-even (k_prep only)
  return (unsigned short)(u >> 16);
}

__device__ __forceinline__ bf16x8 ld_frag(const unsigned short* p) {
  us8_t r = *(const us8_t*)p;
  return __builtin_bit_cast(bf16x8, r);
}

__device__ __forceinline__ float silu(float v) {
  // v * rcp(1+exp(-v)); rcp approx (~1ulp) is far below bf16 noise
  return v * __builtin_amdgcn_rcpf(1.f + __expf(-v));
}

// f32x4 -> 4 bf16 via HW v_cvt_pk_bf16_f32 (RNE), single 8B LDS store.
__device__ __forceinline__ void st_bf4(unsigned short* dst, f32x4 x) {
  *(bf16x4v*)dst = __builtin_convertvector(x, bf16x4v);
}

// Stage 128 rows x 256 cols of fp32 X into LDS as bf16 (padded stride LDA).
// Bounds check hoisted: only the last block takes the slow path.
__device__ __forceinline__ void stage_x(const float* __restrict__ X,
                                        unsigned short* A, int base, int tid) {
  if (base + MT <= N_NODES) {
    #pragma unroll 4
    for (int i = 0; i < 16; ++i) {
      int flat = i * THREADS + tid;    // 0..8191
      int row = flat >> 6;
      int c4 = flat & 63;
      float4 v = *(const float4*)(X + (size_t)(base + row) * DIM + c4 * 4);
      f32x4 f = {v.x, v.y, v.z, v.w};
      st_bf4(A + row * LDA + c4 * 4, f);
    }
  } else {
    #pragma unroll 4
    for (int i = 0; i < 16; ++i) {
      int flat = i * THREADS + tid;
      int row = flat >> 6;
      int c4 = flat & 63;
      float4 v = make_float4(0.f, 0.f, 0.f, 0.f);
      if (base + row < N_NODES)
        v = *(const float4*)(X + (size_t)(base + row) * DIM + c4 * 4);
      f32x4 f = {v.x, v.y, v.z, v.w};
      st_bf4(A + row * LDA + c4 * 4, f);
    }
  }
}

// Transposed GEMM: D[feature][node] = W_tile x X_tile.
// Weights in fragment-linear layout (see k_prep): for 64-feature group wv,
// fragment (ks,u4) lives at ushort offset wv*16384 + (ks*4+u4)*512 + lane*8.
// A 512-thread block has 8 waves of 32 features: wave w uses wv = w>>1,
// u4 = (w&1)*2 + u, folded into the wlane base.
// Depth-2 rotating prefetch: issue ks+2's loads during ks (~240cyc ahead).
// acc[t][u]: node = t*16 + (lane&15), feature = wave*32 + u*16 + (lane>>4)*4 + r.
__device__ __forceinline__ void gemm_k256_T(const unsigned short* __restrict__ wlane,
                                            const unsigned short* alane,
                                            f32x4 acc[NT][NU]) {
  bf16x8 wb[3][NU];
  #pragma unroll
  for (int u = 0; u < NU; ++u) wb[0][u] = ld_frag(wlane + u * 512);
  #pragma unroll
  for (int u = 0; u < NU; ++u) wb[1][u] = ld_frag(wlane + (4 + u) * 512);
  #pragma unroll
  for (int ks = 0; ks < KSTEPS; ++ks) {
    if (ks + 2 < KSTEPS) {
      #pragma unroll
      for (int u = 0; u < NU; ++u)
        wb[(ks + 2) % 3][u] = ld_frag(wlane + ((ks + 2) * 4 + u) * 512);
    }
    #pragma unroll
    for (int t = 0; t < NT; ++t) {
      bf16x8 xfr = ld_frag(alane + t * 16 * LDA + ks * 32);
      #pragma unroll
      for (int u = 0; u < NU; ++u)
        acc[t][u] = __builtin_amdgcn_mfma_f32_16x16x32_bf16(wb[ks % 3][u], xfr, acc[t][u], 0, 0, 0);
    }
  }
}

__device__ __forceinline__ void zero_acc(f32x4 acc[NT][NU]) {
  #pragma unroll
  for (int t = 0; t < NT; ++t)
    #pragma unroll
    for (int u = 0; u < NU; ++u)
      acc[t][u] = (f32x4){0.f, 0.f, 0.f, 0.f};
}

// Kernel 0: blocks 0..63 zero out; block 64 zeros denom; blocks 65..80
// transpose weights to bf16 fragment-linear layout.
__global__ __launch_bounds__(256) void k_prep(
    const float* __restrict__ W1, const float* __restrict__ W2,
    const float* __restrict__ W3, const float* __restrict__ aW1,
    unsigned short* __restrict__ Wb1, unsigned short* __restrict__ Wb2,
    unsigned short* __restrict__ Wb3, unsigned short* __restrict__ aWb1,
    float* __restrict__ out, float* __restrict__ denom) {
  __shared__ float tlds[64][257];
  int b = blockIdx.x, tid = threadIdx.x;
  if (b < 64) {
    float4* o4 = (float4*)out;
    #pragma unroll
    for (int j = 0; j < 4; ++j)
      o4[b * 1024 + j * 256 + tid] = make_float4(0.f, 0.f, 0.f, 0.f);
    return;
  }
  if (b == 64) {
    #pragma unroll
    for (int i = 0; i < 4; ++i) denom[tid * 4 + i] = 0.f;
    return;
  }
  int bb = b - 65;                    // 0..15
  int mat = bb >> 2, kc = bb & 3, k0 = kc * 64;
  const float* W = (mat == 0) ? W1 : (mat == 1) ? W2 : (mat == 2) ? W3 : aW1;
  unsigned short* Wb = (mat == 0) ? Wb1 : (mat == 1) ? Wb2 : (mat == 2) ? Wb3 : aWb1;
  #pragma unroll 8
  for (int i = 0; i < 64; ++i)
    tlds[i][tid] = W[(size_t)(k0 + i) * 256 + tid];
  __syncthreads();
  // emit fragment-linear: 2048 us8 chunks for this k-chunk
  #pragma unroll
  for (int i = 0; i < 8; ++i) {
    int idx = i * 256 + tid;          // 0..2047
    int lane = idx & 63;
    int u = (idx >> 6) & 3;
    int ksl = (idx >> 8) & 1;         // 2 ks values per 64-k chunk
    int wv = idx >> 9;                // 0..3
    int quad = lane >> 4, l15 = lane & 15;
    int row = wv * 64 + u * 16 + l15;
    int ks = kc * 2 + ksl;
    us8_t v;
    #pragma unroll
    for (int j = 0; j < 8; ++j)
      v[j] = f2bf(tlds[ksl * 32 + quad * 8 + j][row]);
    *(us8_t*)(Wb + (size_t)(((wv * 8 + ks) * 4 + u) * 512 + lane * 8)) = v;
  }
}

// Fused heavy kernel: one staging of X, attention GEMM + 3-stage MLP,
// unnormalized weighted segment sums into out + denom.
// 512 threads = 8 waves x 32 features; LDS 68KB -> 2 blocks/CU ->
// 16 waves/CU = 4 waves/SIMD (needs total regs <= 128: acc=64 AGPR).
__global__ __launch_bounds__(THREADS, 4) void k_fused(
    const float* __restrict__ X, const int* __restrict__ batch,
    const unsigned short* __restrict__ aWb1, const float* __restrict__ ab1,
    const float* __restrict__ aW2, const float* __restrict__ ab2,
    const unsigned short* __restrict__ Wb1, const float* __restrict__ b1,
    const unsigned short* __restrict__ Wb2, const float* __restrict__ b2,
    const unsigned short* __restrict__ Wb3,
    float* __restrict__ out, float* __restrict__ denom) {
  __shared__ unsigned short a_lds[MT * LDA];
  __shared__ float l_lds[MT];
  __shared__ float ew0[MT], ew1[MT];
  __shared__ float seg_lds[2];
  int tid = threadIdx.x;
  int base = blockIdx.x * MT;
  stage_x(X, a_lds, base, tid);
  if (tid < MT) l_lds[tid] = 0.f;
  if (tid < 2) seg_lds[tid] = 0.f;
  __syncthreads();

  int wave = tid >> 6, lane = tid & 63, quad = lane >> 4, l15 = lane & 15;
  int wcol0 = wave * 32;
  int fq = wcol0 + quad * 4;          // this lane's feature base for u=0
  const unsigned short* alane = a_lds + l15 * LDA + quad * 8;
  unsigned short* elane = a_lds + l15 * LDA + fq;     // epilogue store base
  // fragment-linear lane base: 64-feature group (wave>>1), sub-half (wave&1)
  int wfoff = (wave >> 1) * 16384 + (wave & 1) * 1024 + lane * 8;
  f32x4 acc[NT][NU];

  // ---- attention logits GEMM ----
  zero_acc(acc);
  gemm_k256_T(aWb1 + wfoff, alane, acc);
  {
    float4 ab1c[NU], aw2c[NU];
    #pragma unroll
    for (int u = 0; u < NU; ++u) {
      ab1c[u] = *(const float4*)(ab1 + fq + u * 16);
      aw2c[u] = *(const float4*)(aW2 + fq + u * 16);
    }
    #pragma unroll
    for (int t = 0; t < NT; ++t) {
      float p = 0.f;
      #pragma unroll
      for (int u = 0; u < NU; ++u) {
        const float* bb = (const float*)&ab1c[u];
        const float* ww = (const float*)&aw2c[u];
        #pragma unroll
        for (int r = 0; r < 4; ++r)
          p += silu(acc[t][u][r] + bb[r]) * ww[r];
      }
      p += __shfl_xor(p, 16); p += __shfl_xor(p, 32);
      if (quad == 0) atomicAdd(&l_lds[t * 16 + l15], p);
    }
  }

  // ---- MLP stage 1: h1 = silu(X @ W1 + b1) ----
  zero_acc(acc);
  gemm_k256_T(Wb1 + wfoff, alane, acc);
  __syncthreads();   // all waves done with a_lds reads AND l_lds atomics
  if (tid < MT) {
    int grow = base + tid;
    float e = 0.f; int ds = 0;
    if (grow < N_NODES) {
      e = __expf(l_lds[tid] + ab2[0]);
      ds = batch[grow] - batch[base];   // 0 or 1 (min seg size 195 > 128)
    }
    ew0[tid] = ds ? 0.f : e;
    ew1[tid] = ds ? e : 0.f;
    if (e != 0.f) atomicAdd(&seg_lds[ds], e);
  }
  {
    float4 bc[NU];
    #pragma unroll
    for (int u = 0; u < NU; ++u) bc[u] = *(const float4*)(b1 + fq + u * 16);
    #pragma unroll
    for (int t = 0; t < NT; ++t)
      #pragma unroll
      for (int u = 0; u < NU; ++u) {
        const float* bb = (const float*)&bc[u];
        f32x4 h;
        #pragma unroll
        for (int r = 0; r < 4; ++r)
          h[r] = silu(acc[t][u][r] + bb[r]);
        st_bf4(elane + t * 16 * LDA + u * 16, h);
      }
  }
  __syncthreads();

  // ---- MLP stage 2: h2 = silu(h1 @ W2 + b2) ----
  zero_acc(acc);
  gemm_k256_T(Wb2 + wfoff, alane, acc);
  __syncthreads();
  {
    float4 bc[NU];
    #pragma unroll
    for (int u = 0; u < NU; ++u) bc[u] = *(const float4*)(b2 + fq + u * 16);
    #pragma unroll
    for (int t = 0; t < NT; ++t)
      #pragma unroll
      for (int u = 0; u < NU; ++u) {
        const float* bb = (const float*)&bc[u];
        f32x4 h;
        #pragma unroll
        for (int r = 0; r < 4; ++r)
          h[r] = silu(acc[t][u][r] + bb[r]);
        st_bf4(elane + t * 16 * LDA + u * 16, h);
      }
  }
  __syncthreads();

  // ---- MLP stage 3: x = h2 @ W3 (+b3 folded into k_final), weighted reduce ----
  zero_acc(acc);
  gemm_k256_T(Wb3 + wfoff, alane, acc);
  {
    float s0a[NU][4], s1a[NU][4];
    #pragma unroll
    for (int u = 0; u < NU; ++u)
      #pragma unroll
      for (int r = 0; r < 4; ++r) { s0a[u][r] = 0.f; s1a[u][r] = 0.f; }
    #pragma unroll
    for (int t = 0; t < NT; ++t) {
      float w0 = ew0[t * 16 + l15];
      float w1 = ew1[t * 16 + l15];
      #pragma unroll
      for (int u = 0; u < NU; ++u)
        #pragma unroll
        for (int r = 0; r < 4; ++r) {
          float x = acc[t][u][r];
          s0a[u][r] += x * w0;
          s1a[u][r] += x * w1;
        }
    }
    int s0 = batch[base];
    #pragma unroll
    for (int u = 0; u < NU; ++u)
      #pragma unroll
      for (int r = 0; r < 4; ++r) {
        float a0 = s0a[u][r];
        a0 += __shfl_xor(a0, 1); a0 += __shfl_xor(a0, 2);
        a0 += __shfl_xor(a0, 4); a0 += __shfl_xor(a0, 8);
        float a1 = s1a[u][r];
        a1 += __shfl_xor(a1, 1); a1 += __shfl_xor(a1, 2);
        a1 += __shfl_xor(a1, 4); a1 += __shfl_xor(a1, 8);
        if (l15 == 0) {
          int col = fq + u * 16 + r;
          atomicAdd(&out[(size_t)s0 * 256 + col], a0);
          if (s0 + 1 < G_SEG && a1 != 0.f)
            atomicAdd(&out[(size_t)(s0 + 1) * 256 + col], a1);
        }
      }
    if (tid < 2) {
      float v = seg_lds[tid];
      if (v != 0.f) atomicAdd(&denom[s0 + tid], v);
    }
  }
}

// Kernel 2: out[g][c] = out[g][c]/denom[g] + b3[c]  (bias commutes with the
// normalized weighted mean: sum(w*b3)/sum(w) = b3)
__global__ __launch_bounds__(256) void k_final(float* __restrict__ out,
                                               const float* __restrict__ denom,
                                               const float* __restrict__ b3) {
  int b = blockIdx.x, tid = threadIdx.x;
  out[b * 256 + tid] = out[b * 256 + tid] * __builtin_amdgcn_rcpf(denom[b]) + b3[tid];
}

extern "C" void kernel_launch(void* const* d_in, const int* in_sizes, int n_in,
                              void* d_out, int out_size, void* d_ws, size_t ws_size,
                              hipStream_t stream) {
  const float* X    = (const float*)d_in[0];
  const int* batch  = (const int*)d_in[1];
  const float* W1  = (const float*)d_in[3];
  const float* b1  = (const float*)d_in[4];
  const float* W2  = (const float*)d_in[5];
  const float* b2  = (const float*)d_in[6];
  const float* W3  = (const float*)d_in[7];
  const float* b3  = (const float*)d_in[8];
  const float* aW1 = (const float*)d_in[9];
  const float* ab1 = (const float*)d_in[10];
  const float* aW2 = (const float*)d_in[11];
  const float* ab2 = (const float*)d_in[12];
  float* out = (float*)d_out;

  char* ws = (char*)d_ws;
  unsigned short* Wb1  = (unsigned short*)(ws);
  unsigned short* Wb2  = (unsigned short*)(ws + 131072);
  unsigned short* Wb3  = (unsigned short*)(ws + 262144);
  unsigned short* aWb1 = (unsigned short*)(ws + 393216);
  float* denom = (float*)(ws + 524288);

  hipLaunchKernelGGL(k_prep, dim3(81), dim3(256), 0, stream,
                     W1, W2, W3, aW1, Wb1, Wb2, Wb3, aWb1, out, denom);
  int nblk = (N_NODES + MT - 1) / MT;  // 1563
  hipLaunchKernelGGL(k_fused, dim3(nblk), dim3(THREADS), 0, stream,
                     X, batch, aWb1, ab1, aW2, ab2,
                     Wb1, b1, Wb2, b2, Wb3, out, denom);
  hipLaunchKernelGGL(k_final, dim3(G_SEG), dim3(256), 0, stream, out, denom, b3);
}